// Round 13
// baseline (222.583 us; speedup 1.0000x reference)
//
#include <hip/hip_runtime.h>
#include <hip/hip_fp16.h>

#define NN 16384
#define EE 524288
#define DDIM 128
#define HDIM 256
#define CDIM 10
#define GG 64
#define MAXD 128

typedef _Float16 h8 __attribute__((ext_vector_type(8)));
typedef float f4 __attribute__((ext_vector_type(4)));
typedef unsigned short su8 __attribute__((ext_vector_type(8)));

// workspace byte offsets
#define OFF_XH   0ull          // 4 MB fp16 x [NN][128]
#define OFF_ELL  4194304ull    // 4 MB ushort ELL [NN][128]
#define OFF_ELLP 8388608ull    // 8 MB uint packed (col | f16w<<16) [NN][128]
#define OFF_H1   16777216ull   // 8 MB fp16 [NN][256]
#define OFF_DEG  25165824ull   // 64 KB int (memset 0 each call)
#define OFF_DIS  25231360ull   // 64 KB float
#define OFF_POOL 25296896ull   // 64 KB (16384 floats)
#define OFF_CNT  25362432ull   // 4 KB (64 floats)
#define OFF_WT1  25366528ull   // 64 KB fp16 Wt1[256][128]
#define OFF_WT2  25432064ull   // 128 KB fp16 Wt2[256][256]

// fused init + edge-append. deg pre-zeroed by hipMemsetAsync.
// grid: 2048 (x->f16) + 128 (Wt1) + 256 (Wt2) + 64 (misc) + 1024 (edges) = 3520
// edges append at slot pos+1; slot 0 is the IMPLICIT self-loop.
__global__ void init_all(const float* __restrict__ x, _Float16* __restrict__ xh,
                         const float* __restrict__ W1, _Float16* __restrict__ wt1,
                         const float* __restrict__ W2, _Float16* __restrict__ wt2,
                         const int* __restrict__ ei, unsigned short* __restrict__ ell,
                         int* __restrict__ deg,
                         float* __restrict__ pooled, float* __restrict__ cnt,
                         const int* __restrict__ batch) {
    int b = blockIdx.x, t = threadIdx.x;
    if (b < 2048) {
        int i = (b * 256 + t) * 4;
        float4 v = *(const float4*)(x + i);
        _Float16 o[4] = {(_Float16)v.x, (_Float16)v.y, (_Float16)v.z, (_Float16)v.w};
        *(ushort4*)(xh + i) = *(ushort4*)o;
    } else if (b < 2176) {
        int i = (b - 2048) * 256 + t;
        int n = i / DDIM, k = i - n * DDIM;
        wt1[i] = (_Float16)W1[k * 256 + n];
    } else if (b < 2432) {
        int i = (b - 2176) * 256 + t;
        int n = i / HDIM, k = i - n * HDIM;
        wt2[i] = (_Float16)W2[k * 256 + n];
    } else if (b < 2496) {
        int r = (b - 2432) * 256 + t;
        pooled[r] = 0.0f;
        if (r < GG) {
            int lo = 0, hi = NN;
            while (lo < hi) { int m = (lo + hi) >> 1; if (batch[m] < r) lo = m + 1; else hi = m; }
            int a = lo;
            lo = 0; hi = NN;
            while (lo < hi) { int m = (lo + hi) >> 1; if (batch[m] < r + 1) lo = m + 1; else hi = m; }
            cnt[r] = (float)(lo - a);
        }
    } else {
        int e = ((b - 2496) * 256 + t) * 2;
        int2 s2 = *(const int2*)(ei + e);
        int2 d2 = *(const int2*)(ei + EE + e);
        int pos = atomicAdd(&deg[s2.x], 1) + 1;
        if (pos < MAXD) ell[s2.x * MAXD + pos] = (unsigned short)d2.x;
        pos = atomicAdd(&deg[s2.y], 1) + 1;
        if (pos < MAXD) ell[s2.y * MAXD + pos] = (unsigned short)d2.y;
    }
}

// one wave per row: O(d^2) dedup; slot 0 = implicit self-loop.
__global__ __launch_bounds__(256) void dedup_kernel(unsigned short* __restrict__ ell,
                                                    int* __restrict__ deg,
                                                    float* __restrict__ dis) {
    int row  = blockIdx.x * 4 + (threadIdx.x >> 6);
    int lane = threadIdx.x & 63;
    int d = deg[row] + 1;
    if (d > MAXD) d = MAXD;
    int c0 = (lane == 0) ? row : ell[row * MAXD + lane];
    int c1 = ell[row * MAXD + 64 + lane];
    bool k0 = lane < d;
    bool k1 = (64 + lane) < d;
    for (int j = 0; j < d - 1; j++) {
        int cj0 = __shfl(c0, j & 63, 64);
        int cj1 = __shfl(c1, j & 63, 64);
        int cj = (j < 64) ? cj0 : cj1;
        if (k0 && lane > j && c0 == cj) k0 = false;
        if (k1 && (64 + lane) > j && c1 == cj) k1 = false;
    }
    unsigned long long m0 = __ballot(k0);
    unsigned long long m1 = __ballot(k1);
    int nd = __popcll(m0) + __popcll(m1);
    unsigned long long below = (lane == 0) ? 0ull : ((~0ull) >> (64 - lane));
    int p0 = __popcll(m0 & below);
    int p1 = __popcll(m0) + __popcll(m1 & below);
    if (k0) ell[row * MAXD + p0] = (unsigned short)c0;
    if (k1) ell[row * MAXD + p1] = (unsigned short)c1;
    if (lane == 0) {
        deg[row] = nd;
        dis[row] = 1.0f / sqrtf((float)nd);
    }
}

// ellp[row][slot] = col | (fp16 dis[col]) << 16 ; zero-weight pad (all 128 slots)
__global__ void pack_kernel(const unsigned short* __restrict__ ell,
                            const int* __restrict__ deg, const float* __restrict__ dis,
                            unsigned* __restrict__ ellp) {
    int i = blockIdx.x * 256 + threadIdx.x;
    int row = i >> 7;
    int slot = i & 127;
    int c = ell[i] & (NN - 1);
    float w = (slot < deg[row]) ? dis[c] : 0.0f;
    _Float16 wh = (_Float16)w;
    ellp[i] = (unsigned)c | ((unsigned)(*(unsigned short*)&wh) << 16);
}

// ---- gather phase: each wave computes RPW rows of y = Ahat @ src into LDS ----
// Indices live in registers (2 coalesced loads/row), broadcast via shfl.
// Pad slots have weight 0 -> uniform trip count, no divergence, no barrier.
template <int KK, int YSTR, int RPW>
__device__ __forceinline__ void gather_rows(const _Float16* __restrict__ src,
                                            const unsigned* __restrict__ ellp,
                                            const int* __restrict__ deg,
                                            const float* __restrict__ dis,
                                            _Float16* ytile, int r0, int t) {
    constexpr int SEG = KK / 8;      // lanes per neighbor (16 or 32)
    constexpr int NS  = 64 / SEG;    // neighbors in flight per instr (4 or 2)
    const int wv = t >> 6, lane = t & 63;
    const int sid = lane / SEG, l = lane % SEG;
    for (int rr = 0; rr < RPW; rr++) {
        const int rowl = wv * RPW + rr;
        const int row = r0 + rowl;
        unsigned c0 = ellp[row * MAXD + lane];
        unsigned c1 = ellp[row * MAXD + 64 + lane];
        const int d = deg[row];
        const int dpad = (d + NS - 1) & ~(NS - 1);
        float acc[8];
#pragma unroll
        for (int j = 0; j < 8; j++) acc[j] = 0.0f;
        for (int k = sid; k < dpad; k += NS) {
            unsigned ua = __shfl(c0, k & 63, 64);
            unsigned ub = __shfl(c1, k & 63, 64);
            unsigned u = (k < 64) ? ua : ub;
            unsigned short wb = (unsigned short)(u >> 16);
            float wgt = (float)(*(_Float16*)&wb);
            su8 hv = *(const su8*)(src + (size_t)(u & 0xFFFF) * KK + l * 8);
#pragma unroll
            for (int j = 0; j < 8; j++) {
                unsigned short hb = hv[j];
                acc[j] = fmaf(wgt, (float)(*(_Float16*)&hb), acc[j]);
            }
        }
        if (SEG == 16) {
#pragma unroll
            for (int j = 0; j < 8; j++) acc[j] += __shfl_xor(acc[j], 16, 64);
        }
#pragma unroll
        for (int j = 0; j < 8; j++) acc[j] += __shfl_xor(acc[j], 32, 64);
        if (lane < SEG) {
            float dr = dis[row];
            _Float16 o[8];
#pragma unroll
            for (int j = 0; j < 8; j++) o[j] = (_Float16)(dr * acc[j]);
            *(su8*)&ytile[rowl * YSTR + l * 8] = *(su8*)o;
        }
    }
}

#define BSTR 40

// fused layer 1: ytile = Ahat@x (32 rows), then h1[32,256] = relu(ytile@W1+b1)
// 512 thr / 8 waves; wave (wm= wv>>2 in {0,1}, wn = wv&3): 16 rows x 64 cols.
__global__ __launch_bounds__(512) void fused_layer1(
        const _Float16* __restrict__ xh, const unsigned* __restrict__ ellp,
        const int* __restrict__ deg, const float* __restrict__ dis,
        const _Float16* __restrict__ Wt, const float* __restrict__ bias,
        _Float16* __restrict__ H) {
    __shared__ __align__(16) _Float16 ytile[32 * 136];   // 8.7 KB, reused as Cs
    __shared__ __align__(16) _Float16 Bs[256 * BSTR];    // 20.5 KB
    const int r0 = blockIdx.x * 32;
    const int t = threadIdx.x;
    gather_rows<DDIM, 136, 4>(xh, ellp, deg, dis, ytile, r0, t);

    const int lane = t & 63, wv = t >> 6;
    const int wm = wv >> 2, wn = wv & 3;
    const int qm = lane & 15, qk = lane >> 4;
    f4 acc[4];
#pragma unroll
    for (int j = 0; j < 4; j++) acc[j] = (f4){0.f, 0.f, 0.f, 0.f};

    for (int k0 = 0; k0 < DDIM; k0 += 32) {
        __syncthreads();
        {
            int n = t >> 1, ko = (t & 1) * 16;
            *(su8*)&Bs[n * BSTR + ko]     = *(const su8*)(Wt + (size_t)n * DDIM + k0 + ko);
            *(su8*)&Bs[n * BSTR + ko + 8] = *(const su8*)(Wt + (size_t)n * DDIM + k0 + ko + 8);
        }
        __syncthreads();
        h8 afr = *(const h8*)&ytile[(wm * 16 + qm) * 136 + k0 + qk * 8];
#pragma unroll
        for (int j = 0; j < 4; j++) {
            h8 bfr = *(const h8*)&Bs[(wn * 64 + j * 16 + qm) * BSTR + qk * 8];
            acc[j] = __builtin_amdgcn_mfma_f32_16x16x32_f16(afr, bfr, acc[j], 0, 0, 0);
        }
    }

    float bv[4];
#pragma unroll
    for (int j = 0; j < 4; j++) bv[j] = bias[wn * 64 + j * 16 + qm];

    // two half-col passes through ytile-as-Cs (stride 136, 128 cols each)
#pragma unroll
    for (int pass = 0; pass < 2; pass++) {
        __syncthreads();
        if ((wn >> 1) == pass) {
            int lc = (wn & 1) * 64;
#pragma unroll
            for (int j = 0; j < 4; j++) {
#pragma unroll
                for (int rr = 0; rr < 4; rr++) {
                    int lr = wm * 16 + qk * 4 + rr;
                    ytile[lr * 136 + lc + j * 16 + qm] =
                        (_Float16)fmaxf(acc[j][rr] + bv[j], 0.0f);
                }
            }
        }
        __syncthreads();
        {
            int row = t >> 4, cg = (t & 15) * 8;
            *(su8*)(H + (size_t)(r0 + row) * 256 + pass * 128 + cg) =
                *(const su8*)&ytile[row * 136 + cg];
        }
    }
}

// fused layer 2: ytile = Ahat@h1 (32 rows), then pooled += relu(ytile@W2+b2)
#define NG 8
__global__ __launch_bounds__(512) void fused_layer2(
        const _Float16* __restrict__ h1, const unsigned* __restrict__ ellp,
        const int* __restrict__ deg, const float* __restrict__ dis,
        const _Float16* __restrict__ Wt, const float* __restrict__ bias,
        const int* __restrict__ batch, float* __restrict__ pooled) {
    __shared__ __align__(16) _Float16 ytile[32 * 264];   // 16.9 KB
    __shared__ __align__(16) _Float16 Bs[256 * BSTR];    // 20.5 KB
    __shared__ float pools[NG * 264];                    // 8.4 KB
    __shared__ int sb[32];
    const int r0 = blockIdx.x * 32;
    const int t = threadIdx.x;
    if (t < 32) sb[t] = batch[r0 + t];
    for (int i = t; i < NG * 264; i += 512) pools[i] = 0.0f;
    gather_rows<HDIM, 264, 4>(h1, ellp, deg, dis, ytile, r0, t);

    const int lane = t & 63, wv = t >> 6;
    const int wm = wv >> 2, wn = wv & 3;
    const int qm = lane & 15, qk = lane >> 4;
    f4 acc[4];
#pragma unroll
    for (int j = 0; j < 4; j++) acc[j] = (f4){0.f, 0.f, 0.f, 0.f};

    for (int k0 = 0; k0 < HDIM; k0 += 32) {
        __syncthreads();
        {
            int n = t >> 1, ko = (t & 1) * 16;
            *(su8*)&Bs[n * BSTR + ko]     = *(const su8*)(Wt + (size_t)n * HDIM + k0 + ko);
            *(su8*)&Bs[n * BSTR + ko + 8] = *(const su8*)(Wt + (size_t)n * HDIM + k0 + ko + 8);
        }
        __syncthreads();
        h8 afr = *(const h8*)&ytile[(wm * 16 + qm) * 264 + k0 + qk * 8];
#pragma unroll
        for (int j = 0; j < 4; j++) {
            h8 bfr = *(const h8*)&Bs[(wn * 64 + j * 16 + qm) * BSTR + qk * 8];
            acc[j] = __builtin_amdgcn_mfma_f32_16x16x32_f16(afr, bfr, acc[j], 0, 0, 0);
        }
    }

    float bv[4];
#pragma unroll
    for (int j = 0; j < 4; j++) bv[j] = bias[wn * 64 + j * 16 + qm];
    const int g0 = sb[0];
#pragma unroll
    for (int j = 0; j < 4; j++) {
        int lc = wn * 64 + j * 16 + qm;
#pragma unroll
        for (int rr = 0; rr < 4; rr++) {
            int lr = wm * 16 + qk * 4 + rr;
            int gi = min(sb[lr] - g0, NG - 1);
            float v = fmaxf(acc[j][rr] + bv[j], 0.0f);
            atomicAdd(&pools[gi * 264 + lc], v);
        }
    }
    __syncthreads();
    const int ng = min(sb[31] - g0 + 1, NG);
    for (int i2 = t; i2 < ng * 256; i2 += 512) {
        int gi = i2 >> 8, c = i2 & 255;
        float v = pools[gi * 264 + c];
        if (v != 0.0f) atomicAdd(&pooled[(g0 + gi) * 256 + c], v);
    }
}

// out[g,c] = (pooled[g,:]/cnt[g]) . Wc[:,c] + bc[c]
__global__ void head_kernel(const float* __restrict__ pooled,
                            const float* __restrict__ cnt,
                            const float* __restrict__ Wc,
                            const float* __restrict__ bc,
                            float* __restrict__ out) {
    int g = blockIdx.x;
    int l = threadIdx.x;  // 64
    float inv = 1.0f / fmaxf(cnt[g], 1.0f);
    float acc[CDIM];
#pragma unroll
    for (int c = 0; c < CDIM; c++) acc[c] = 0.0f;
    for (int t = l; t < 256; t += 64) {
        float pv = pooled[g * 256 + t] * inv;
#pragma unroll
        for (int c = 0; c < CDIM; c++) acc[c] = fmaf(pv, Wc[t * CDIM + c], acc[c]);
    }
#pragma unroll
    for (int c = 0; c < CDIM; c++) {
        float v = acc[c];
        for (int off = 32; off > 0; off >>= 1) v += __shfl_down(v, off, 64);
        if (l == 0) out[g * CDIM + c] = v + bc[c];
    }
}

extern "C" void kernel_launch(void* const* d_in, const int* in_sizes, int n_in,
                              void* d_out, int out_size, void* d_ws, size_t ws_size,
                              hipStream_t stream) {
    const float* x  = (const float*)d_in[0];
    const int*   ei = (const int*)d_in[1];
    const int*   batch = (const int*)d_in[2];
    const float* W1 = (const float*)d_in[3];
    const float* b1 = (const float*)d_in[4];
    const float* W2 = (const float*)d_in[5];
    const float* b2 = (const float*)d_in[6];
    const float* Wc = (const float*)d_in[7];
    const float* bc = (const float*)d_in[8];
    float* out = (float*)d_out;

    char* ws = (char*)d_ws;
    _Float16* xh   = (_Float16*)(ws + OFF_XH);
    unsigned short* ell = (unsigned short*)(ws + OFF_ELL);
    unsigned* ellp = (unsigned*)(ws + OFF_ELLP);
    _Float16* h1   = (_Float16*)(ws + OFF_H1);
    int*   deg     = (int*)(ws + OFF_DEG);
    float* dis     = (float*)(ws + OFF_DIS);
    float* pooled  = (float*)(ws + OFF_POOL);
    float* cnt     = (float*)(ws + OFF_CNT);
    _Float16* wt1  = (_Float16*)(ws + OFF_WT1);
    _Float16* wt2  = (_Float16*)(ws + OFF_WT2);

    // 0) deg = 0
    hipMemsetAsync(deg, 0, NN * sizeof(int), stream);
    // 1) fused init (x->f16, Wt1, Wt2, pooled=0, cnt, edge append)
    init_all<<<3520, 256, 0, stream>>>(x, xh, W1, wt1, W2, wt2, ei, ell, deg,
                                       pooled, cnt, batch);
    // 2) per-row wave dedup (slot0 = implicit self loop) -> deg, dis
    dedup_kernel<<<NN / 4, 256, 0, stream>>>(ell, deg, dis);
    // 3) packed weighted ELL
    pack_kernel<<<(NN * MAXD) / 256, 256, 0, stream>>>(ell, deg, dis, ellp);
    // 4) fused layer1: h1 = relu((Ahat@x)@W1 + b1)
    fused_layer1<<<NN / 32, 512, 0, stream>>>(xh, ellp, deg, dis, wt1, b1, h1);
    // 5) fused layer2: pooled += relu((Ahat@h1)@W2 + b2), run-length pooled
    fused_layer2<<<NN / 32, 512, 0, stream>>>(h1, ellp, deg, dis, wt2, b2,
                                              batch, pooled);
    // 6) head
    head_kernel<<<GG, 64, 0, stream>>>(pooled, cnt, Wc, bc, out);
}

// Round 14
// 213.006 us; speedup vs baseline: 1.0450x; 1.0450x over previous
//
#include <hip/hip_runtime.h>
#include <hip/hip_fp16.h>

#define NN 16384
#define EE 524288
#define DDIM 128
#define HDIM 256
#define CDIM 10
#define GG 64
#define MAXD 128

typedef _Float16 h8 __attribute__((ext_vector_type(8)));
typedef float f4 __attribute__((ext_vector_type(4)));
typedef unsigned short su8 __attribute__((ext_vector_type(8)));

// workspace byte offsets (~38 MB total)
#define OFF_XH   0ull          // 4 MB fp16 x [NN][128]
#define OFF_ELL  4194304ull    // 4 MB ushort ELL [NN][128]
#define OFF_ELLP 8388608ull    // 8 MB uint packed (col | f16w<<16) [NN][128]
#define OFF_Y1H  16777216ull   // 4 MB fp16 [NN][128]
#define OFF_H1   20971520ull   // 8 MB fp16 [NN][256]
#define OFF_Y2H  29360128ull   // 8 MB fp16 [NN][256]
#define OFF_DEG  37748736ull   // 64 KB int (memset 0 each call)
#define OFF_DIS  37814272ull   // 64 KB float
#define OFF_POOL 37879808ull   // 64 KB (16384 floats)
#define OFF_CNT  37945344ull   // 4 KB (64 floats)
#define OFF_WT1  37949440ull   // 64 KB fp16 Wt1[256][128]
#define OFF_WT2  38014976ull   // 128 KB fp16 Wt2[256][256]

// fused init + edge-append. deg pre-zeroed by hipMemsetAsync.
// grid: 2048 (x->f16) + 128 (Wt1) + 256 (Wt2) + 64 (misc) + 1024 (edges) = 3520
// edges append at slot pos+1; slot 0 is the IMPLICIT self-loop (dedup knows).
__global__ void init_all(const float* __restrict__ x, _Float16* __restrict__ xh,
                         const float* __restrict__ W1, _Float16* __restrict__ wt1,
                         const float* __restrict__ W2, _Float16* __restrict__ wt2,
                         const int* __restrict__ ei, unsigned short* __restrict__ ell,
                         int* __restrict__ deg,
                         float* __restrict__ pooled, float* __restrict__ cnt,
                         const int* __restrict__ batch) {
    int b = blockIdx.x, t = threadIdx.x;
    if (b < 2048) {                       // x -> fp16 (float4 per thread)
        int i = (b * 256 + t) * 4;
        float4 v = *(const float4*)(x + i);
        _Float16 o[4] = {(_Float16)v.x, (_Float16)v.y, (_Float16)v.z, (_Float16)v.w};
        *(ushort4*)(xh + i) = *(ushort4*)o;
    } else if (b < 2176) {                // Wt1[n][k] = W1[k][n]
        int i = (b - 2048) * 256 + t;
        int n = i / DDIM, k = i - n * DDIM;
        wt1[i] = (_Float16)W1[k * 256 + n];
    } else if (b < 2432) {                // Wt2[n][k] = W2[k][n]
        int i = (b - 2176) * 256 + t;
        int n = i / HDIM, k = i - n * HDIM;
        wt2[i] = (_Float16)W2[k * 256 + n];
    } else if (b < 2496) {                // per-row misc + cnt
        int r = (b - 2432) * 256 + t;
        pooled[r] = 0.0f;
        if (r < GG) {
            int lo = 0, hi = NN;
            while (lo < hi) { int m = (lo + hi) >> 1; if (batch[m] < r) lo = m + 1; else hi = m; }
            int a = lo;
            lo = 0; hi = NN;
            while (lo < hi) { int m = (lo + hi) >> 1; if (batch[m] < r + 1) lo = m + 1; else hi = m; }
            cnt[r] = (float)(lo - a);
        }
    } else {                              // edge append, 2 edges/thread
        int e = ((b - 2496) * 256 + t) * 2;
        int2 s2 = *(const int2*)(ei + e);
        int2 d2 = *(const int2*)(ei + EE + e);
        int pos = atomicAdd(&deg[s2.x], 1) + 1;
        if (pos < MAXD) ell[s2.x * MAXD + pos] = (unsigned short)d2.x;
        pos = atomicAdd(&deg[s2.y], 1) + 1;
        if (pos < MAXD) ell[s2.y * MAXD + pos] = (unsigned short)d2.y;
    }
}

// one wave per row: O(d^2) dedup via broadcast-compare, ballot compaction.
// slot 0 = implicit self-loop (row id); entries = deg[row]+1.
__global__ __launch_bounds__(256) void dedup_kernel(unsigned short* __restrict__ ell,
                                                    int* __restrict__ deg,
                                                    float* __restrict__ dis) {
    int row  = blockIdx.x * 4 + (threadIdx.x >> 6);
    int lane = threadIdx.x & 63;
    int d = deg[row] + 1;
    if (d > MAXD) d = MAXD;
    int c0 = (lane == 0) ? row : ell[row * MAXD + lane];
    int c1 = ell[row * MAXD + 64 + lane];
    bool k0 = lane < d;
    bool k1 = (64 + lane) < d;
    for (int j = 0; j < d - 1; j++) {
        int cj0 = __shfl(c0, j & 63, 64);
        int cj1 = __shfl(c1, j & 63, 64);
        int cj = (j < 64) ? cj0 : cj1;
        if (k0 && lane > j && c0 == cj) k0 = false;
        if (k1 && (64 + lane) > j && c1 == cj) k1 = false;
    }
    unsigned long long m0 = __ballot(k0);
    unsigned long long m1 = __ballot(k1);
    int nd = __popcll(m0) + __popcll(m1);
    unsigned long long below = (lane == 0) ? 0ull : ((~0ull) >> (64 - lane));
    int p0 = __popcll(m0 & below);
    int p1 = __popcll(m0) + __popcll(m1 & below);
    if (k0) ell[row * MAXD + p0] = (unsigned short)c0;
    if (k1) ell[row * MAXD + p1] = (unsigned short)c1;
    if (lane == 0) {
        deg[row] = nd;
        dis[row] = 1.0f / sqrtf((float)nd);
    }
}

// ellp[row][slot] = col | (fp16 dis[col]) << 16 ; zero-weight pad
__global__ void pack_kernel(const unsigned short* __restrict__ ell,
                            const int* __restrict__ deg, const float* __restrict__ dis,
                            unsigned* __restrict__ ellp) {
    int i = blockIdx.x * 256 + threadIdx.x;  // NN*128
    int row = i >> 7;
    int slot = i & 127;
    int c = ell[i] & (NN - 1);
    float w = (slot < deg[row]) ? dis[c] : 0.0f;
    _Float16 wh = (_Float16)w;
    ellp[i] = (unsigned)c | ((unsigned)(*(unsigned short*)&wh) << 16);
}

// y[row,:] = (fp16)(dis[row] * sum_k w_k * src[col_k,:])
// FOUR rows per block, 512 threads (2 waves/row) -- amortizes index staging,
// barriers and launch overhead. Gather loop identical to the proven R11 form:
// lane loads ushort8 (16B); COLS=128: 16 lanes/neighbor, 4 neighbors/instr;
// COLS=256: 32 lanes/neighbor, 2/instr. unroll 4.
template <int COLS>
__global__ __launch_bounds__(512) void spmm_f16(const _Float16* __restrict__ src,
                                                const unsigned* __restrict__ ellp,
                                                const int* __restrict__ deg,
                                                const float* __restrict__ dis,
                                                _Float16* __restrict__ y) {
    constexpr int SEG = COLS / 8;    // lanes per neighbor
    constexpr int NS  = 64 / SEG;    // neighbors per wave instr
    constexpr int ST  = 2 * NS;      // gather streams per row (2 waves/row)
    __shared__ unsigned scw[4][MAXD];
    __shared__ float red[4][ST][COLS];
    const int row0 = blockIdx.x * 4;
    const int t    = threadIdx.x;
    const int wv   = t >> 6;
    const int ri   = wv >> 1;        // row within block (0..3)
    const int wp   = wv & 1;         // wave index within row
    const int lane = t & 63;
    const int sid  = lane / SEG;
    const int l    = lane % SEG;
    const int row  = row0 + ri;
    scw[t >> 7][t & 127] = ellp[(size_t)(row0 + (t >> 7)) * MAXD + (t & 127)];
    __syncthreads();
    const int d = deg[row];

    float acc[8];
#pragma unroll
    for (int j = 0; j < 8; j++) acc[j] = 0.0f;

    const int stream = wp * NS + sid;
#pragma unroll 4
    for (int k = stream; k < d; k += ST) {
        unsigned u = scw[ri][k];
        int col = u & 0xFFFF;
        unsigned short wb = (unsigned short)(u >> 16);
        float wgt = (float)(*(_Float16*)&wb);
        su8 hv = *(const su8*)(src + (size_t)col * COLS + l * 8);
#pragma unroll
        for (int j = 0; j < 8; j++) {
            unsigned short hb = hv[j];
            acc[j] = fmaf(wgt, (float)(*(_Float16*)&hb), acc[j]);
        }
    }
    *(f4*)&red[ri][stream][l * 8]     = (f4){acc[0], acc[1], acc[2], acc[3]};
    *(f4*)&red[ri][stream][l * 8 + 4] = (f4){acc[4], acc[5], acc[6], acc[7]};
    __syncthreads();
    for (int o = t; o < 4 * COLS; o += 512) {
        int rr = o / COLS, c = o % COLS;
        float s = 0.0f;
#pragma unroll
        for (int q = 0; q < ST; q++) s += red[rr][q][c];
        y[(size_t)(row0 + rr) * COLS + c] = (_Float16)(dis[row0 + rr] * s);
    }
}

// ================= MFMA GEMM: 128x64 tile, 256 thr / 4 waves ================
#define ASTR 40   // f16 stride (80 B, 16B-aligned)
#define BSTR 40

#define MFMA_PROLOG                                                            \
    const int r0 = blockIdx.x * 128;                                           \
    const int c0 = blockIdx.y * 64;                                            \
    const int t = threadIdx.x;                                                 \
    const int lane = t & 63, wv = t >> 6;                                      \
    const int wm = wv >> 1, wn = wv & 1;                                       \
    const int qm = lane & 15, qk = lane >> 4;                                  \
    f4 acc[4][2];                                                              \
    _Pragma("unroll") for (int i = 0; i < 4; i++)                              \
        _Pragma("unroll") for (int j = 0; j < 2; j++)                          \
            acc[i][j] = (f4){0.f, 0.f, 0.f, 0.f};

#define MFMA_KLOOP(Aptr, Wtptr, K)                                             \
    for (int k0 = 0; k0 < K; k0 += 32) {                                       \
        __syncthreads();                                                       \
        {                                                                      \
            int r = t >> 1, ko = (t & 1) * 16;                                 \
            const su8* srcA = (const su8*)(Aptr + (size_t)(r0 + r) * K + k0 + ko); \
            su8 a0 = srcA[0], a1 = srcA[1];                                    \
            *(su8*)&As[r * ASTR + ko]     = a0;                                \
            *(su8*)&As[r * ASTR + ko + 8] = a1;                                \
            int n = t >> 2, ko2 = (t & 3) * 8;                                 \
            *(su8*)&Bs[n * BSTR + ko2] =                                       \
                *(const su8*)(Wtptr + (size_t)(c0 + n) * K + k0 + ko2);        \
        }                                                                      \
        __syncthreads();                                                       \
        h8 bfr[2];                                                             \
        _Pragma("unroll") for (int j = 0; j < 2; j++)                          \
            bfr[j] = *(const h8*)&Bs[(wn * 32 + j * 16 + qm) * BSTR + qk * 8]; \
        _Pragma("unroll") for (int i = 0; i < 4; i++) {                        \
            h8 afr = *(const h8*)&As[(wm * 64 + i * 16 + qm) * ASTR + qk * 8]; \
            _Pragma("unroll") for (int j = 0; j < 2; j++)                      \
                acc[i][j] = __builtin_amdgcn_mfma_f32_16x16x32_f16(            \
                    afr, bfr[j], acc[i][j], 0, 0, 0);                          \
        }                                                                      \
    }

// GEMM1: h1 = relu(y1 @ W1 + b1) -> fp16 [NN][256]
template <int K>
__global__ __launch_bounds__(256) void gemm_mfma_f16(
        const _Float16* __restrict__ A, const _Float16* __restrict__ Wt,
        const float* __restrict__ bias, _Float16* __restrict__ H) {
    __shared__ __align__(16) _Float16 As[128 * ASTR];
    __shared__ __align__(16) _Float16 Bs[64 * BSTR];
    __shared__ __align__(16) _Float16 Cs[128 * 72];
    MFMA_PROLOG
    MFMA_KLOOP(A, Wt, K)

    float bv[2];
#pragma unroll
    for (int j = 0; j < 2; j++) bv[j] = bias[c0 + wn * 32 + j * 16 + qm];
#pragma unroll
    for (int i = 0; i < 4; i++)
#pragma unroll
        for (int j = 0; j < 2; j++) {
            int lc = wn * 32 + j * 16 + qm;
#pragma unroll
            for (int rr = 0; rr < 4; rr++) {
                int lr = wm * 64 + i * 16 + qk * 4 + rr;
                Cs[lr * 72 + lc] = (_Float16)fmaxf(acc[i][j][rr] + bv[j], 0.0f);
            }
        }
    __syncthreads();
    {
        int r = t >> 1, half_ = t & 1;
        _Float16* dst = H + (size_t)(r0 + r) * 256 + c0 + half_ * 32;
        const _Float16* srcc = &Cs[r * 72 + half_ * 32];
#pragma unroll
        for (int q = 0; q < 4; q++)
            *(su8*)(dst + q * 8) = *(const su8*)(srcc + q * 8);
    }
}

// GEMM2 + fused mean-pool numerator (no C materialization).
#define NG 8
template <int K>
__global__ __launch_bounds__(256) void gemm_mfma_pool(
        const _Float16* __restrict__ A, const _Float16* __restrict__ Wt,
        const float* __restrict__ bias, const int* __restrict__ batch,
        float* __restrict__ pooled) {
    __shared__ __align__(16) _Float16 As[128 * ASTR];
    __shared__ __align__(16) _Float16 Bs[64 * BSTR];
    __shared__ float pools[NG][68];
    __shared__ int sb[128];
    MFMA_PROLOG
    if (t < 128) sb[t] = batch[r0 + t];
    for (int i = t; i < NG * 68; i += 256) ((float*)pools)[i] = 0.0f;
    MFMA_KLOOP(A, Wt, K)

    float bv[2];
#pragma unroll
    for (int j = 0; j < 2; j++) bv[j] = bias[c0 + wn * 32 + j * 16 + qm];
    __syncthreads();
    const int g0 = sb[0];
#pragma unroll
    for (int i = 0; i < 4; i++)
#pragma unroll
        for (int j = 0; j < 2; j++) {
            int lc = wn * 32 + j * 16 + qm;
#pragma unroll
            for (int rr = 0; rr < 4; rr++) {
                int lr = wm * 64 + i * 16 + qk * 4 + rr;
                int gi = min(sb[lr] - g0, NG - 1);
                float v = fmaxf(acc[i][j][rr] + bv[j], 0.0f);
                atomicAdd(&pools[gi][lc], v);
            }
        }
    __syncthreads();
    const int ng = min(sb[127] - g0 + 1, NG);
    for (int i2 = t; i2 < ng * 64; i2 += 256) {
        int gi = i2 >> 6, c = i2 & 63;
        float v = pools[gi][c];
        if (v != 0.0f) atomicAdd(&pooled[(g0 + gi) * 256 + c0 + c], v);
    }
}

// out[g,c] = (pooled[g,:]/cnt[g]) . Wc[:,c] + bc[c]
__global__ void head_kernel(const float* __restrict__ pooled,
                            const float* __restrict__ cnt,
                            const float* __restrict__ Wc,
                            const float* __restrict__ bc,
                            float* __restrict__ out) {
    int g = blockIdx.x;
    int l = threadIdx.x;  // 64
    float inv = 1.0f / fmaxf(cnt[g], 1.0f);
    float acc[CDIM];
#pragma unroll
    for (int c = 0; c < CDIM; c++) acc[c] = 0.0f;
    for (int t = l; t < 256; t += 64) {
        float pv = pooled[g * 256 + t] * inv;
#pragma unroll
        for (int c = 0; c < CDIM; c++) acc[c] = fmaf(pv, Wc[t * CDIM + c], acc[c]);
    }
#pragma unroll
    for (int c = 0; c < CDIM; c++) {
        float v = acc[c];
        for (int off = 32; off > 0; off >>= 1) v += __shfl_down(v, off, 64);
        if (l == 0) out[g * CDIM + c] = v + bc[c];
    }
}

extern "C" void kernel_launch(void* const* d_in, const int* in_sizes, int n_in,
                              void* d_out, int out_size, void* d_ws, size_t ws_size,
                              hipStream_t stream) {
    const float* x  = (const float*)d_in[0];
    const int*   ei = (const int*)d_in[1];
    const int*   batch = (const int*)d_in[2];
    const float* W1 = (const float*)d_in[3];
    const float* b1 = (const float*)d_in[4];
    const float* W2 = (const float*)d_in[5];
    const float* b2 = (const float*)d_in[6];
    const float* Wc = (const float*)d_in[7];
    const float* bc = (const float*)d_in[8];
    float* out = (float*)d_out;

    char* ws = (char*)d_ws;
    _Float16* xh   = (_Float16*)(ws + OFF_XH);
    unsigned short* ell = (unsigned short*)(ws + OFF_ELL);
    unsigned* ellp = (unsigned*)(ws + OFF_ELLP);
    _Float16* y1h  = (_Float16*)(ws + OFF_Y1H);
    _Float16* h1   = (_Float16*)(ws + OFF_H1);
    _Float16* y2h  = (_Float16*)(ws + OFF_Y2H);
    int*   deg     = (int*)(ws + OFF_DEG);
    float* dis     = (float*)(ws + OFF_DIS);
    float* pooled  = (float*)(ws + OFF_POOL);
    float* cnt     = (float*)(ws + OFF_CNT);
    _Float16* wt1  = (_Float16*)(ws + OFF_WT1);
    _Float16* wt2  = (_Float16*)(ws + OFF_WT2);

    // 0) deg = 0 (async memset is graph-capture safe)
    hipMemsetAsync(deg, 0, NN * sizeof(int), stream);
    // 1) fused init (x->f16, Wt1, Wt2, pooled=0, cnt, edge append)
    init_all<<<3520, 256, 0, stream>>>(x, xh, W1, wt1, W2, wt2, ei, ell, deg,
                                       pooled, cnt, batch);
    // 2) per-row wave dedup (slot0 = implicit self loop) -> deg, dis
    dedup_kernel<<<NN / 4, 256, 0, stream>>>(ell, deg, dis);
    // 3) packed weighted ELL (col | f16 dis[col] << 16)
    pack_kernel<<<(NN * MAXD) / 256, 256, 0, stream>>>(ell, deg, dis, ellp);
    // 4) SpMM1: y1h = Ahat @ xh  [N,128], 4 rows/block
    spmm_f16<DDIM><<<NN / 4, 512, 0, stream>>>(xh, ellp, deg, dis, y1h);
    // 5) GEMM1 (MFMA): h1 = relu(y1h @ W1 + b1) -> fp16 [NN][256]
    {
        dim3 grid(NN / 128, 256 / 64);
        gemm_mfma_f16<DDIM><<<grid, 256, 0, stream>>>(y1h, wt1, b1, h1);
    }
    // 6) SpMM2: y2h = Ahat @ h1  [N,256], 4 rows/block
    spmm_f16<HDIM><<<NN / 4, 512, 0, stream>>>(h1, ellp, deg, dis, y2h);
    // 7) GEMM2 (MFMA) + fused pooling numerator
    {
        dim3 grid(NN / 128, 256 / 64);
        gemm_mfma_pool<HDIM><<<grid, 256, 0, stream>>>(y2h, wt2, b2, batch, pooled);
    }
    // 8) head
    head_kernel<<<GG, 64, 0, stream>>>(pooled, cnt, Wc, bc, out);
}